// Round 16
// baseline (248.567 us; speedup 1.0000x reference)
//
#include <hip/hip_runtime.h>
#include <hip/hip_bf16.h>
#include <stdint.h>

#define NN    4096
#define INF_  256
#define HEADS 4
#define HID   64
#define OUTC  256
#define NEG   0.2f
#define L2E   1.44269504f

#define BI     32
#define JSPLIT 8
#define NJ     (NN / JSPLIT)

typedef short bf16x8 __attribute__((ext_vector_type(8)));
typedef float f32x4  __attribute__((ext_vector_type(4)));

// ---- float <-> order-preserving uint encoding (for atomicMax on f32) ----
__device__ __forceinline__ uint32_t ford(float x){
  uint32_t u = __float_as_uint(x);
  return (u & 0x80000000u) ? ~u : (u | 0x80000000u);
}
__device__ __forceinline__ float funord(uint32_t e){
  uint32_t u = (e & 0x80000000u) ? (e & 0x7fffffffu) : ~e;
  return __uint_as_float(u);
}
__device__ __forceinline__ ushort bf16u(float f){
  __hip_bfloat16 b = __float2bfloat16(f);
  return *reinterpret_cast<ushort*>(&b);
}

__device__ __forceinline__ uint32_t pack16(int4 v0, int4 v1, int4 v2, int4 v3){
  uint32_t b = 0;
  b |= (v0.x ? 0x0001u : 0u); b |= (v0.y ? 0x0002u : 0u);
  b |= (v0.z ? 0x0004u : 0u); b |= (v0.w ? 0x0008u : 0u);
  b |= (v1.x ? 0x0010u : 0u); b |= (v1.y ? 0x0020u : 0u);
  b |= (v1.z ? 0x0040u : 0u); b |= (v1.w ? 0x0080u : 0u);
  b |= (v2.x ? 0x0100u : 0u); b |= (v2.y ? 0x0200u : 0u);
  b |= (v2.z ? 0x0400u : 0u); b |= (v2.w ? 0x0800u : 0u);
  b |= (v3.x ? 0x1000u : 0u); b |= (v3.y ? 0x2000u : 0u);
  b |= (v3.z ? 0x4000u : 0u); b |= (v3.w ? 0x8000u : 0u);
  return b;
}

// ---- fused prep (r15 verbatim): blocks 0..255 g-GEMM, 256..2303 pack ----
__launch_bounds__(256)
__global__ void k_prep(const int* __restrict__ adj, const float* __restrict__ hmat,
                       const float* __restrict__ W, const float* __restrict__ aw,
                       ushort* __restrict__ bmb, short* __restrict__ gT,
                       float* __restrict__ slT2, float* __restrict__ srT2,
                       uint32_t* __restrict__ srmax2){
  __shared__ float hsT[64][68];
  __shared__ float wsT[64][68];
  __shared__ float smax_l[16];
  int bid = blockIdx.x;
  int t   = threadIdx.x;

  if (bid >= 256){
    int row = (bid - 256) * 2;
    const int* p0 = adj + (size_t)row*NN + t*16;
    const int* p1 = p0 + NN;
    int4 a0 = *(const int4*)(p0);      int4 a1 = *(const int4*)(p0 + 4);
    int4 a2 = *(const int4*)(p0 + 8);  int4 a3 = *(const int4*)(p0 + 12);
    int4 b0 = *(const int4*)(p1);      int4 b1 = *(const int4*)(p1 + 4);
    int4 b2 = *(const int4*)(p1 + 8);  int4 b3 = *(const int4*)(p1 + 12);
    bmb[(size_t)row*256 + t]       = (ushort)pack16(a0, a1, a2, a3);
    bmb[(size_t)(row + 1)*256 + t] = (ushort)pack16(b0, b1, b2, b3);
    return;
  }

  int tx = t & 15, ty = t >> 4;
  int r0 = (bid & 63) * 64;
  int cb = bid >> 6;
  int c0 = cb * 64;
  float acc[4][4] = {};

  for (int k0 = 0; k0 < INF_; k0 += 64){
    int row = t >> 2, kc = (t & 3) * 16;
    #pragma unroll
    for (int u = 0; u < 4; u++){
      float4 v = *(const float4*)&hmat[(r0 + row)*INF_ + k0 + kc + 4*u];
      hsT[kc + 4*u + 0][row] = v.x;
      hsT[kc + 4*u + 1][row] = v.y;
      hsT[kc + 4*u + 2][row] = v.z;
      hsT[kc + 4*u + 3][row] = v.w;
    }
    #pragma unroll
    for (int u = 0; u < 4; u++){
      float4 v = *(const float4*)&W[(c0 + row)*INF_ + k0 + kc + 4*u];
      wsT[kc + 4*u + 0][row] = v.x;
      wsT[kc + 4*u + 1][row] = v.y;
      wsT[kc + 4*u + 2][row] = v.z;
      wsT[kc + 4*u + 3][row] = v.w;
    }
    __syncthreads();
    #pragma unroll 8
    for (int k = 0; k < 64; k++){
      float4 hv = *(const float4*)&hsT[k][ty*4];
      float4 wv = *(const float4*)&wsT[k][tx*4];
      float ha[4] = {hv.x, hv.y, hv.z, hv.w};
      float wa[4] = {wv.x, wv.y, wv.z, wv.w};
      #pragma unroll
      for (int a_ = 0; a_ < 4; a_++)
        #pragma unroll
        for (int b_ = 0; b_ < 4; b_++)
          acc[a_][b_] = fmaf(ha[a_], wa[b_], acc[a_][b_]);
    }
    __syncthreads();
  }

  float alv[4], arv[4];
  #pragma unroll
  for (int j = 0; j < 4; j++){ alv[j] = aw[tx*4 + j]; arv[j] = aw[64 + tx*4 + j]; }
  float rmax = -3.4e38f;
  #pragma unroll
  for (int qi = 0; qi < 4; qi++){
    int r = r0 + ty*4 + qi;
    float slp = 0.f, srp = 0.f;
    #pragma unroll
    for (int j = 0; j < 4; j++){
      slp = fmaf(acc[qi][j], alv[j], slp);
      srp = fmaf(acc[qi][j], arv[j], srp);
    }
    #pragma unroll
    for (int m = 1; m < 16; m <<= 1){
      slp += __shfl_xor(slp, m, 64);
      srp += __shfl_xor(srp, m, 64);
    }
    if (tx == 0){
      slT2[(size_t)cb*NN + r] = slp * L2E;
      srT2[(size_t)cb*NN + r] = srp * L2E;
      rmax = fmaxf(rmax, srp * L2E);
    }
  }
  if (tx == 0) smax_l[ty] = rmax;

  float* T = (float*)hsT;
  #pragma unroll
  for (int qi = 0; qi < 4; qi++)
    #pragma unroll
    for (int j = 0; j < 4; j++)
      T[(tx*4 + j)*65 + ty*4 + qi] = acc[qi][j];
  __syncthreads();
  if (t == 0){
    float m = smax_l[0];
    #pragma unroll
    for (int i = 1; i < 16; i++) m = fmaxf(m, smax_l[i]);
    atomicMax(srmax2 + cb, ford(m));
  }
  int c = t >> 2, rb = (t & 3) * 16;
  ushort u16[16];
  #pragma unroll
  for (int v = 0; v < 16; v++) u16[v] = bf16u(T[c*65 + rb + v]);
  *(uint4*)&gT[(size_t)(c0 + c)*NN + r0 + rb]     = *(uint4*)&u16[0];
  *(uint4*)&gT[(size_t)(c0 + c)*NN + r0 + rb + 8] = *(uint4*)&u16[8];
}

// ---- fused masked-softmax attention: 8 waves = 4 heads x 2 j-halves.
//      Per-wave loop byte-identical to r15 champion (m=2, 2-deep reg-dbuf B,
//      LDS-staged bm+sr prefetched a step ahead, ones-MFMA den, v_perm pack),
//      but 8 steps over a 256-j half. Cross-half LDS reduction epilogue. ----
__launch_bounds__(512, 8)
__global__ void k_attn(const short* __restrict__ gT, const float* __restrict__ slT2,
                       const float* __restrict__ srT2, const uint32_t* __restrict__ srmax2,
                       const uint32_t* __restrict__ bm,
                       __hip_bfloat16* __restrict__ num_p, float* __restrict__ den_p){
  __shared__ float    srs[4][512];      // [head][j - jbB]
  __shared__ uint32_t bmlds[32 * 18];   // [row][word] stride 18
  __shared__ float    red[16][256];     // reduction: [elem][h*64+l], conflict-free
  int t  = threadIdx.x;
  int w  = t >> 6, l = t & 63;
  int h  = w & 3, jh = w >> 2;
  int lr = l & 15, lg = l >> 4;
  int i0 = blockIdx.x * BI;
  int js = blockIdx.y;
  int jbB = js * NJ;                    // block j-base (512 wide)
  int jb  = jbB + jh * 256;             // wave j-base (256 wide)

  // stage sr slice + bitmask tile (512 threads, one op each)
  {
    int hh = t >> 7, jj = (t & 127) * 4;
    *(float4*)&srs[hh][jj] = *(const float4*)&srT2[(size_t)hh*NN + jbB + jj];
    int r = t >> 4, wd = t & 15;
    bmlds[r*18 + wd] = bm[(size_t)(i0 + r)*128 + (jbB >> 5) + wd];
  }

  float srmaxh = funord(srmax2[h]);
  float d1[2], cc[2];
  #pragma unroll
  for (int m = 0; m < 2; m++){
    float slv = slT2[(size_t)h*NN + i0 + m*16 + lr];
    float xx  = slv + srmaxh;
    float msh = fmaxf(xx, NEG * xx);
    d1[m] = slv - msh;
    cc[m] = (NEG - 1.0f) * msh;
  }
  __syncthreads();

  f32x4 acc[2][4] = {};
  f32x4 dacc[2]   = {};
  bf16x8 ones;
  #pragma unroll
  for (int q = 0; q < 8; q++) ones[q] = (short)0x3F80;

  const short* gTh = gT + (size_t)h*HID*NN;
  const short* bp[4];
  #pragma unroll
  for (int n = 0; n < 4; n++)
    bp[n] = gTh + (size_t)(n*16 + lr)*NN + jb + lg*8;

  bf16x8 Bb[2][4];
  #pragma unroll
  for (int n = 0; n < 4; n++){
    Bb[0][n] = *(const bf16x8*)(bp[n]);
    Bb[1][n] = *(const bf16x8*)(bp[n] + 32);
  }

  // step-0 LDS operands (wave's half: words jh*8.., sr offset jh*256)
  float4 s0c = *(const float4*)&srs[h][jh*256 + lg*8];
  float4 s1c = *(const float4*)&srs[h][jh*256 + lg*8 + 4];
  uint32_t w0c = bmlds[lr*18 + jh*8];
  uint32_t w1c = bmlds[(16 + lr)*18 + jh*8];

  #pragma unroll
  for (int s = 0; s < 8; s++){
    float4 s0n = s0c, s1n = s1c;
    uint32_t w0n = 0, w1n = 0;
    if (s < 7){
      s0n = *(const float4*)&srs[h][jh*256 + (s+1)*32 + lg*8];
      s1n = *(const float4*)&srs[h][jh*256 + (s+1)*32 + lg*8 + 4];
      w0n = bmlds[lr*18 + jh*8 + s + 1];
      w1n = bmlds[(16 + lr)*18 + jh*8 + s + 1];
    }
    float sr8[8] = {s0c.x, s0c.y, s0c.z, s0c.w, s1c.x, s1c.y, s1c.z, s1c.w};

    bf16x8 A[2];
    #pragma unroll
    for (int m = 0; m < 2; m++){
      uint32_t word = (m ? w1c : w0c) >> (lg*8);
      uint32_t pk[4];
      #pragma unroll
      for (int p = 0; p < 4; p++){
        float z0 = d1[m] + sr8[2*p];
        float z1 = d1[m] + sr8[2*p + 1];
        float v0 = __builtin_amdgcn_exp2f(fmaxf(z0, fmaf(NEG, z0, cc[m])));
        float v1 = __builtin_amdgcn_exp2f(fmaxf(z1, fmaf(NEG, z1, cc[m])));
        int m0 = (int)(word << (31 - 2*p)) >> 31;
        int m1 = (int)(word << (30 - 2*p)) >> 31;
        v0 = __uint_as_float(__float_as_uint(v0) & (uint32_t)m0);
        v1 = __uint_as_float(__float_as_uint(v1) & (uint32_t)m1);
        uint32_t u0 = __float_as_uint(v0) + 0x8000u;
        uint32_t u1 = __float_as_uint(v1) + 0x8000u;
        pk[p] = __builtin_amdgcn_perm(u1, u0, 0x07060302u);
      }
      A[m] = *(bf16x8*)pk;
    }

    __builtin_amdgcn_s_setprio(1);
    dacc[0] = __builtin_amdgcn_mfma_f32_16x16x32_bf16(A[0], ones, dacc[0], 0, 0, 0);
    #pragma unroll
    for (int n = 0; n < 4; n++)
      acc[0][n] = __builtin_amdgcn_mfma_f32_16x16x32_bf16(A[0], Bb[s & 1][n], acc[0][n], 0, 0, 0);
    dacc[1] = __builtin_amdgcn_mfma_f32_16x16x32_bf16(A[1], ones, dacc[1], 0, 0, 0);
    #pragma unroll
    for (int n = 0; n < 4; n++)
      acc[1][n] = __builtin_amdgcn_mfma_f32_16x16x32_bf16(A[1], Bb[s & 1][n], acc[1][n], 0, 0, 0);
    __builtin_amdgcn_s_setprio(0);

    if (s + 2 < 8){
      #pragma unroll
      for (int n = 0; n < 4; n++)
        Bb[s & 1][n] = *(const bf16x8*)(bp[n] + (s + 2)*32);
    }
    s0c = s0n; s1c = s1n; w0c = w0n; w1c = w1n;
  }

  // ---- cross-j-half reduction: jh=1 -> LDS -> jh=0 adds ----
  __syncthreads();                       // all compute done; bmlds/srs dead
  float* dred = (float*)bmlds;           // 512 B reuse for dacc rows
  // round 1: n = 0,1 (+ dacc)
  if (jh == 1){
    #pragma unroll
    for (int m = 0; m < 2; m++)
      #pragma unroll
      for (int n = 0; n < 2; n++)
        #pragma unroll
        for (int r = 0; r < 4; r++)
          red[m*8 + n*4 + r][h*64 + l] = acc[m][n][r];
    if (lr == 0)
      #pragma unroll
      for (int m = 0; m < 2; m++)
        #pragma unroll
        for (int r = 0; r < 4; r++)
          dred[h*32 + m*16 + lg*4 + r] = dacc[m][r];
  }
  __syncthreads();
  if (jh == 0){
    #pragma unroll
    for (int m = 0; m < 2; m++)
      #pragma unroll
      for (int n = 0; n < 2; n++)
        #pragma unroll
        for (int r = 0; r < 4; r++)
          acc[m][n][r] += red[m*8 + n*4 + r][h*64 + l];
    if (lr == 0)
      #pragma unroll
      for (int m = 0; m < 2; m++)
        #pragma unroll
        for (int r = 0; r < 4; r++)
          dacc[m][r] += dred[h*32 + m*16 + lg*4 + r];
  }
  __syncthreads();
  // round 2: n = 2,3
  if (jh == 1){
    #pragma unroll
    for (int m = 0; m < 2; m++)
      #pragma unroll
      for (int n = 2; n < 4; n++)
        #pragma unroll
        for (int r = 0; r < 4; r++)
          red[m*8 + (n-2)*4 + r][h*64 + l] = acc[m][n][r];
  }
  __syncthreads();
  if (jh == 0){
    #pragma unroll
    for (int m = 0; m < 2; m++)
      #pragma unroll
      for (int n = 2; n < 4; n++)
        #pragma unroll
        for (int r = 0; r < 4; r++)
          acc[m][n][r] += red[m*8 + (n-2)*4 + r][h*64 + l];

    // num partials (bf16): row = i0+m*16+lg*4+r, col = h*64+n*16+lr
    #pragma unroll
    for (int m = 0; m < 2; m++)
      #pragma unroll
      for (int n = 0; n < 4; n++)
        #pragma unroll
        for (int r = 0; r < 4; r++)
          num_p[((size_t)js*NN + i0 + m*16 + lg*4 + r)*OUTC + h*HID + n*16 + lr] =
              __float2bfloat16(acc[m][n][r]);

    if (lr == 0)
      #pragma unroll
      for (int m = 0; m < 2; m++)
        #pragma unroll
        for (int r = 0; r < 4; r++)
          den_p[((size_t)js*4 + h)*NN + i0 + m*16 + lg*4 + r] = dacc[m][r];
  }
}

// ---- combine partials: out = sum(num)/sum(den), 2 cols/thread ----
__global__ void k_comb(const __hip_bfloat16* __restrict__ num_p,
                       const float* __restrict__ den_p, float* __restrict__ out){
  int t  = threadIdx.x;
  int r  = blockIdx.x*2 + (t >> 7);
  int c2 = (t & 127) * 2;
  int h  = c2 >> 6;
  float s0 = 0.f, s1 = 0.f, d = 0.f;
  #pragma unroll
  for (int js = 0; js < JSPLIT; js++){
    uint32_t u = *(const uint32_t*)&num_p[((size_t)js*NN + r)*OUTC + c2];
    s0 += __uint_as_float(u << 16);
    s1 += __uint_as_float(u & 0xffff0000u);
  }
  #pragma unroll
  for (int js = 0; js < JSPLIT; js++)
    d += den_p[((size_t)js*4 + h)*NN + r];
  float inv = 1.0f / d;
  *(float2*)&out[(size_t)r*OUTC + c2] = make_float2(s0*inv, s1*inv);
}

extern "C" void kernel_launch(void* const* d_in, const int* in_sizes, int n_in,
                              void* d_out, int out_size, void* d_ws, size_t ws_size,
                              hipStream_t stream){
  const float* hmat = (const float*)d_in[0];
  const int*   adj  = (const int*)d_in[1];     // int32 layout confirmed in r1
  const float* W    = (const float*)d_in[2];
  const float* aw   = (const float*)d_in[3];
  float* out = (float*)d_out;
  char*  ws  = (char*)d_ws;

  // ws layout (bytes), total ~21.6 MB
  uint32_t* srmax2 = (uint32_t*)(ws);                      // 64 B
  float*    slT2   = (float*)(ws + 1024);                  // 64 KB
  float*    srT2   = (float*)(ws + 66560);                 // 64 KB
  short*    gT     = (short*)(ws + 132096);                // 2 MB   [256][4096] bf16
  float*    den_p  = (float*)(ws + 2229248);               // 512 KB [8][4][4096]
  __hip_bfloat16* num_p = (__hip_bfloat16*)(ws + 2753536); // 16.75 MB [8][4096][256]
  uint32_t* bmask  = (uint32_t*)(ws + 19530752);           // 2 MB   [4096][128] (byte-packed)

  hipMemsetAsync(ws, 0, 64, stream);   // srmax2 init
  hipLaunchKernelGGL(k_prep, dim3(2304), dim3(256), 0, stream,
                     adj, hmat, W, aw, (ushort*)bmask, gT, slT2, srT2, srmax2);
  hipLaunchKernelGGL(k_attn, dim3(NN/BI, JSPLIT), dim3(512), 0, stream,
                     gT, slT2, srT2, srmax2, bmask, num_p, den_p);
  hipLaunchKernelGGL(k_comb, dim3(NN/2), dim3(256), 0, stream, num_p, den_p, out);
}

// Round 17
// 74.005 us; speedup vs baseline: 3.3588x; 3.3588x over previous
//
#include <hip/hip_runtime.h>
#include <hip/hip_bf16.h>
#include <stdint.h>

#define NN    4096
#define INF_  256
#define HEADS 4
#define HID   64
#define OUTC  256
#define NEG   0.2f
#define L2E   1.44269504f

#define BI     32

typedef short bf16x8 __attribute__((ext_vector_type(8)));
typedef float f32x4  __attribute__((ext_vector_type(4)));

// ---- float <-> order-preserving uint encoding (for atomicMax on f32) ----
__device__ __forceinline__ uint32_t ford(float x){
  uint32_t u = __float_as_uint(x);
  return (u & 0x80000000u) ? ~u : (u | 0x80000000u);
}
__device__ __forceinline__ float funord(uint32_t e){
  uint32_t u = (e & 0x80000000u) ? (e & 0x7fffffffu) : ~e;
  return __uint_as_float(u);
}
__device__ __forceinline__ ushort bf16u(float f){
  __hip_bfloat16 b = __float2bfloat16(f);
  return *reinterpret_cast<ushort*>(&b);
}

__device__ __forceinline__ uint32_t pack16(int4 v0, int4 v1, int4 v2, int4 v3){
  uint32_t b = 0;
  b |= (v0.x ? 0x0001u : 0u); b |= (v0.y ? 0x0002u : 0u);
  b |= (v0.z ? 0x0004u : 0u); b |= (v0.w ? 0x0008u : 0u);
  b |= (v1.x ? 0x0010u : 0u); b |= (v1.y ? 0x0020u : 0u);
  b |= (v1.z ? 0x0040u : 0u); b |= (v1.w ? 0x0080u : 0u);
  b |= (v2.x ? 0x0100u : 0u); b |= (v2.y ? 0x0200u : 0u);
  b |= (v2.z ? 0x0400u : 0u); b |= (v2.w ? 0x0800u : 0u);
  b |= (v3.x ? 0x1000u : 0u); b |= (v3.y ? 0x2000u : 0u);
  b |= (v3.z ? 0x4000u : 0u); b |= (v3.w ? 0x8000u : 0u);
  return b;
}

// ---- fused prep (r15 verbatim): blocks 0..255 g-GEMM, 256..2303 pack ----
__launch_bounds__(256)
__global__ void k_prep(const int* __restrict__ adj, const float* __restrict__ hmat,
                       const float* __restrict__ W, const float* __restrict__ aw,
                       ushort* __restrict__ bmb, short* __restrict__ gT,
                       float* __restrict__ slT2, float* __restrict__ srT2,
                       uint32_t* __restrict__ srmax2){
  __shared__ float hsT[64][68];
  __shared__ float wsT[64][68];
  __shared__ float smax_l[16];
  int bid = blockIdx.x;
  int t   = threadIdx.x;

  if (bid >= 256){
    int row = (bid - 256) * 2;
    const int* p0 = adj + (size_t)row*NN + t*16;
    const int* p1 = p0 + NN;
    int4 a0 = *(const int4*)(p0);      int4 a1 = *(const int4*)(p0 + 4);
    int4 a2 = *(const int4*)(p0 + 8);  int4 a3 = *(const int4*)(p0 + 12);
    int4 b0 = *(const int4*)(p1);      int4 b1 = *(const int4*)(p1 + 4);
    int4 b2 = *(const int4*)(p1 + 8);  int4 b3 = *(const int4*)(p1 + 12);
    bmb[(size_t)row*256 + t]       = (ushort)pack16(a0, a1, a2, a3);
    bmb[(size_t)(row + 1)*256 + t] = (ushort)pack16(b0, b1, b2, b3);
    return;
  }

  int tx = t & 15, ty = t >> 4;
  int r0 = (bid & 63) * 64;
  int cb = bid >> 6;
  int c0 = cb * 64;
  float acc[4][4] = {};

  for (int k0 = 0; k0 < INF_; k0 += 64){
    int row = t >> 2, kc = (t & 3) * 16;
    #pragma unroll
    for (int u = 0; u < 4; u++){
      float4 v = *(const float4*)&hmat[(r0 + row)*INF_ + k0 + kc + 4*u];
      hsT[kc + 4*u + 0][row] = v.x;
      hsT[kc + 4*u + 1][row] = v.y;
      hsT[kc + 4*u + 2][row] = v.z;
      hsT[kc + 4*u + 3][row] = v.w;
    }
    #pragma unroll
    for (int u = 0; u < 4; u++){
      float4 v = *(const float4*)&W[(c0 + row)*INF_ + k0 + kc + 4*u];
      wsT[kc + 4*u + 0][row] = v.x;
      wsT[kc + 4*u + 1][row] = v.y;
      wsT[kc + 4*u + 2][row] = v.z;
      wsT[kc + 4*u + 3][row] = v.w;
    }
    __syncthreads();
    #pragma unroll 8
    for (int k = 0; k < 64; k++){
      float4 hv = *(const float4*)&hsT[k][ty*4];
      float4 wv = *(const float4*)&wsT[k][tx*4];
      float ha[4] = {hv.x, hv.y, hv.z, hv.w};
      float wa[4] = {wv.x, wv.y, wv.z, wv.w};
      #pragma unroll
      for (int a_ = 0; a_ < 4; a_++)
        #pragma unroll
        for (int b_ = 0; b_ < 4; b_++)
          acc[a_][b_] = fmaf(ha[a_], wa[b_], acc[a_][b_]);
    }
    __syncthreads();
  }

  float alv[4], arv[4];
  #pragma unroll
  for (int j = 0; j < 4; j++){ alv[j] = aw[tx*4 + j]; arv[j] = aw[64 + tx*4 + j]; }
  float rmax = -3.4e38f;
  #pragma unroll
  for (int qi = 0; qi < 4; qi++){
    int r = r0 + ty*4 + qi;
    float slp = 0.f, srp = 0.f;
    #pragma unroll
    for (int j = 0; j < 4; j++){
      slp = fmaf(acc[qi][j], alv[j], slp);
      srp = fmaf(acc[qi][j], arv[j], srp);
    }
    #pragma unroll
    for (int m = 1; m < 16; m <<= 1){
      slp += __shfl_xor(slp, m, 64);
      srp += __shfl_xor(srp, m, 64);
    }
    if (tx == 0){
      slT2[(size_t)cb*NN + r] = slp * L2E;
      srT2[(size_t)cb*NN + r] = srp * L2E;
      rmax = fmaxf(rmax, srp * L2E);
    }
  }
  if (tx == 0) smax_l[ty] = rmax;

  float* T = (float*)hsT;
  #pragma unroll
  for (int qi = 0; qi < 4; qi++)
    #pragma unroll
    for (int j = 0; j < 4; j++)
      T[(tx*4 + j)*65 + ty*4 + qi] = acc[qi][j];
  __syncthreads();
  if (t == 0){
    float m = smax_l[0];
    #pragma unroll
    for (int i = 1; i < 16; i++) m = fmaxf(m, smax_l[i]);
    atomicMax(srmax2 + cb, ford(m));
  }
  int c = t >> 2, rb = (t & 3) * 16;
  ushort u16[16];
  #pragma unroll
  for (int v = 0; v < 16; v++) u16[v] = bf16u(T[c*65 + rb + v]);
  *(uint4*)&gT[(size_t)(c0 + c)*NN + r0 + rb]     = *(uint4*)&u16[0];
  *(uint4*)&gT[(size_t)(c0 + c)*NN + r0 + rb + 8] = *(uint4*)&u16[8];
}

// ---- fused masked-softmax attention, templated on JSPLIT.
//      Per-wave structure = r15 champion verbatim (m=2, 2-deep reg-dbuf B,
//      LDS-staged bm+sr prefetched a step ahead, ones-MFMA den, v_perm pack).
//      JS=16 halves per-block j-range (8 steps) and doubles the grid. ----
template<int JS>
__launch_bounds__(256, 4)
__global__ void k_attn(const short* __restrict__ gT, const float* __restrict__ slT2,
                       const float* __restrict__ srT2, const uint32_t* __restrict__ srmax2,
                       const uint32_t* __restrict__ bm,
                       __hip_bfloat16* __restrict__ num_p, float* __restrict__ den_p){
  constexpr int NJ_   = NN / JS;        // j per block
  constexpr int NSTEP = NJ_ / 32;       // MFMA steps
  constexpr int NW    = NJ_ / 32;       // bm words per row
  constexpr int BST   = NW + 2;         // bmlds stride (even, conflict-safe)
  __shared__ uint32_t bmlds[32 * BST];
  __shared__ float    srs[4][NJ_];
  int t  = threadIdx.x;
  int h  = t >> 6, l = t & 63;
  int lr = l & 15, lg = l >> 4;
  int i0 = blockIdx.x * BI;
  int jb = blockIdx.y * NJ_;
  int js = blockIdx.y;

  // stage sr slice (wave h loads its head's NJ_ scores) + bitmask tile
  #pragma unroll
  for (int jj = l*4; jj < NJ_; jj += 256)
    *(float4*)&srs[h][jj] = *(const float4*)&srT2[(size_t)h*NN + jb + jj];
  #pragma unroll
  for (int idx = t; idx < 32*NW; idx += 256)
    bmlds[(idx/NW)*BST + (idx % NW)] =
        bm[(size_t)(i0 + idx/NW)*128 + (jb >> 5) + (idx % NW)];

  float srmaxh = funord(srmax2[h]);
  float d1[2], cc[2];
  #pragma unroll
  for (int m = 0; m < 2; m++){
    float slv = slT2[(size_t)h*NN + i0 + m*16 + lr];
    float xx  = slv + srmaxh;
    float msh = fmaxf(xx, NEG * xx);
    d1[m] = slv - msh;              // z = d1 + sr
    cc[m] = (NEG - 1.0f) * msh;     // neg branch: NEG*z + cc
  }
  __syncthreads();

  f32x4 acc[2][4] = {};
  f32x4 dacc[2]   = {};
  bf16x8 ones;
  #pragma unroll
  for (int q = 0; q < 8; q++) ones[q] = (short)0x3F80;

  const short* gTh = gT + (size_t)h*HID*NN;
  const short* bp[4];
  #pragma unroll
  for (int n = 0; n < 4; n++)
    bp[n] = gTh + (size_t)(n*16 + lr)*NN + jb + lg*8;

  bf16x8 Bb[2][4];
  #pragma unroll
  for (int n = 0; n < 4; n++){
    Bb[0][n] = *(const bf16x8*)(bp[n]);
    Bb[1][n] = *(const bf16x8*)(bp[n] + 32);
  }

  // step-0 LDS operands
  float4 s0c = *(const float4*)&srs[h][lg*8];
  float4 s1c = *(const float4*)&srs[h][lg*8 + 4];
  uint32_t w0c = bmlds[lr*BST];
  uint32_t w1c = bmlds[(16 + lr)*BST];

  #pragma unroll
  for (int s = 0; s < NSTEP; s++){
    // prefetch next step's LDS operands
    float4 s0n = s0c, s1n = s1c;
    uint32_t w0n = 0, w1n = 0;
    if (s < NSTEP - 1){
      s0n = *(const float4*)&srs[h][(s+1)*32 + lg*8];
      s1n = *(const float4*)&srs[h][(s+1)*32 + lg*8 + 4];
      w0n = bmlds[lr*BST + s + 1];
      w1n = bmlds[(16 + lr)*BST + s + 1];
    }
    float sr8[8] = {s0c.x, s0c.y, s0c.z, s0c.w, s1c.x, s1c.y, s1c.z, s1c.w};

    bf16x8 A[2];
    #pragma unroll
    for (int m = 0; m < 2; m++){
      uint32_t word = (m ? w1c : w0c) >> (lg*8);
      uint32_t pk[4];
      #pragma unroll
      for (int p = 0; p < 4; p++){
        float z0 = d1[m] + sr8[2*p];
        float z1 = d1[m] + sr8[2*p + 1];
        float v0 = __builtin_amdgcn_exp2f(fmaxf(z0, fmaf(NEG, z0, cc[m])));
        float v1 = __builtin_amdgcn_exp2f(fmaxf(z1, fmaf(NEG, z1, cc[m])));
        int m0 = (int)(word << (31 - 2*p)) >> 31;     // bit 2p   -> all-ones/zero
        int m1 = (int)(word << (30 - 2*p)) >> 31;     // bit 2p+1
        v0 = __uint_as_float(__float_as_uint(v0) & (uint32_t)m0);
        v1 = __uint_as_float(__float_as_uint(v1) & (uint32_t)m1);
        uint32_t u0 = __float_as_uint(v0) + 0x8000u;
        uint32_t u1 = __float_as_uint(v1) + 0x8000u;
        pk[p] = __builtin_amdgcn_perm(u1, u0, 0x07060302u);  // {u1.hi16, u0.hi16}
      }
      A[m] = *(bf16x8*)pk;
    }

    __builtin_amdgcn_s_setprio(1);
    dacc[0] = __builtin_amdgcn_mfma_f32_16x16x32_bf16(A[0], ones, dacc[0], 0, 0, 0);
    #pragma unroll
    for (int n = 0; n < 4; n++)
      acc[0][n] = __builtin_amdgcn_mfma_f32_16x16x32_bf16(A[0], Bb[s & 1][n], acc[0][n], 0, 0, 0);
    dacc[1] = __builtin_amdgcn_mfma_f32_16x16x32_bf16(A[1], ones, dacc[1], 0, 0, 0);
    #pragma unroll
    for (int n = 0; n < 4; n++)
      acc[1][n] = __builtin_amdgcn_mfma_f32_16x16x32_bf16(A[1], Bb[s & 1][n], acc[1][n], 0, 0, 0);
    __builtin_amdgcn_s_setprio(0);

    if (s + 2 < NSTEP){
      #pragma unroll
      for (int n = 0; n < 4; n++)
        Bb[s & 1][n] = *(const bf16x8*)(bp[n] + (s + 2)*32);
    }
    s0c = s0n; s1c = s1n; w0c = w0n; w1c = w1n;
  }

  // num partials (bf16): row = i0+m*16+lg*4+r, col = h*64+n*16+lr
  #pragma unroll
  for (int m = 0; m < 2; m++)
    #pragma unroll
    for (int n = 0; n < 4; n++)
      #pragma unroll
      for (int r = 0; r < 4; r++)
        num_p[((size_t)js*NN + i0 + m*16 + lg*4 + r)*OUTC + h*HID + n*16 + lr] =
            __float2bfloat16(acc[m][n][r]);

  // den partials from ones-MFMA: row m*16+lg*4+r value sits in dacc[m][r] (any lr)
  if (lr == 0)
    #pragma unroll
    for (int m = 0; m < 2; m++)
      #pragma unroll
      for (int r = 0; r < 4; r++)
        den_p[((size_t)js*4 + h)*NN + i0 + m*16 + lg*4 + r] = dacc[m][r];
}

// ---- combine partials: out = sum(num)/sum(den), 2 cols/thread ----
template<int JS>
__global__ void k_comb(const __hip_bfloat16* __restrict__ num_p,
                       const float* __restrict__ den_p, float* __restrict__ out){
  int t  = threadIdx.x;
  int r  = blockIdx.x*2 + (t >> 7);
  int c2 = (t & 127) * 2;
  int h  = c2 >> 6;
  float s0 = 0.f, s1 = 0.f, d = 0.f;
  #pragma unroll
  for (int js = 0; js < JS; js++){
    uint32_t u = *(const uint32_t*)&num_p[((size_t)js*NN + r)*OUTC + c2];
    s0 += __uint_as_float(u << 16);
    s1 += __uint_as_float(u & 0xffff0000u);
  }
  #pragma unroll
  for (int js = 0; js < JS; js++)
    d += den_p[((size_t)js*4 + h)*NN + r];
  float inv = 1.0f / d;
  *(float2*)&out[(size_t)r*OUTC + c2] = make_float2(s0*inv, s1*inv);
}

extern "C" void kernel_launch(void* const* d_in, const int* in_sizes, int n_in,
                              void* d_out, int out_size, void* d_ws, size_t ws_size,
                              hipStream_t stream){
  const float* hmat = (const float*)d_in[0];
  const int*   adj  = (const int*)d_in[1];     // int32 layout confirmed in r1
  const float* W    = (const float*)d_in[2];
  const float* aw   = (const float*)d_in[3];
  float* out = (float*)d_out;
  char*  ws  = (char*)d_ws;

  uint32_t* srmax2 = (uint32_t*)(ws);          // 64 B
  float*    slT2   = (float*)(ws + 1024);      // 64 KB
  float*    srT2   = (float*)(ws + 66560);     // 64 KB
  short*    gT     = (short*)(ws + 132096);    // 2 MB [256][4096] bf16

  hipMemsetAsync(ws, 0, 64, stream);   // srmax2 init

  // JS=16 layout needs: den 1MB @2229248, num 32MB @3277824, bmask 2MB @36832256
  const size_t NEED16 = 38929408;
  if (ws_size >= NEED16){
    float*          den_p = (float*)(ws + 2229248);
    __hip_bfloat16* num_p = (__hip_bfloat16*)(ws + 3277824);
    uint32_t*       bmask = (uint32_t*)(ws + 36832256);
    hipLaunchKernelGGL(k_prep, dim3(2304), dim3(256), 0, stream,
                       adj, hmat, W, aw, (ushort*)bmask, gT, slT2, srT2, srmax2);
    hipLaunchKernelGGL((k_attn<16>), dim3(NN/BI, 16), dim3(256), 0, stream,
                       gT, slT2, srT2, srmax2, bmask, num_p, den_p);
    hipLaunchKernelGGL((k_comb<16>), dim3(NN/2), dim3(256), 0, stream,
                       num_p, den_p, out);
  } else {
    // r15 fallback layout (proven, ~21.6 MB)
    float*          den_p = (float*)(ws + 2229248);
    __hip_bfloat16* num_p = (__hip_bfloat16*)(ws + 2753536);
    uint32_t*       bmask = (uint32_t*)(ws + 19530752);
    hipLaunchKernelGGL(k_prep, dim3(2304), dim3(256), 0, stream,
                       adj, hmat, W, aw, (ushort*)bmask, gT, slT2, srT2, srmax2);
    hipLaunchKernelGGL((k_attn<8>), dim3(NN/BI, 8), dim3(256), 0, stream,
                       gT, slT2, srT2, srmax2, bmask, num_p, den_p);
    hipLaunchKernelGGL((k_comb<8>), dim3(NN/2), dim3(256), 0, stream,
                       num_p, den_p, out);
  }
}

// Round 18
// 68.034 us; speedup vs baseline: 3.6536x; 1.0878x over previous
//
#include <hip/hip_runtime.h>
#include <hip/hip_bf16.h>
#include <stdint.h>

#define NN    4096
#define INF_  256
#define HEADS 4
#define HID   64
#define OUTC  256
#define NEG   0.2f
#define L2E   1.44269504f

#define BI     32
#define JSPLIT 8
#define NJ     (NN / JSPLIT)

typedef short  bf16x8 __attribute__((ext_vector_type(8)));
typedef float  f32x4  __attribute__((ext_vector_type(4)));
typedef unsigned short u16x2 __attribute__((ext_vector_type(2)));
typedef short  s16x2 __attribute__((ext_vector_type(2)));

// ---- float <-> order-preserving uint encoding (for atomicMax on f32) ----
__device__ __forceinline__ uint32_t ford(float x){
  uint32_t u = __float_as_uint(x);
  return (u & 0x80000000u) ? ~u : (u | 0x80000000u);
}
__device__ __forceinline__ float funord(uint32_t e){
  uint32_t u = (e & 0x80000000u) ? (e & 0x7fffffffu) : ~e;
  return __uint_as_float(u);
}
__device__ __forceinline__ ushort bf16u(float f){
  __hip_bfloat16 b = __float2bfloat16(f);
  return *reinterpret_cast<ushort*>(&b);
}

__device__ __forceinline__ uint32_t pack16(int4 v0, int4 v1, int4 v2, int4 v3){
  uint32_t b = 0;
  b |= (v0.x ? 0x0001u : 0u); b |= (v0.y ? 0x0002u : 0u);
  b |= (v0.z ? 0x0004u : 0u); b |= (v0.w ? 0x0008u : 0u);
  b |= (v1.x ? 0x0010u : 0u); b |= (v1.y ? 0x0020u : 0u);
  b |= (v1.z ? 0x0040u : 0u); b |= (v1.w ? 0x0080u : 0u);
  b |= (v2.x ? 0x0100u : 0u); b |= (v2.y ? 0x0200u : 0u);
  b |= (v2.z ? 0x0400u : 0u); b |= (v2.w ? 0x0800u : 0u);
  b |= (v3.x ? 0x1000u : 0u); b |= (v3.y ? 0x2000u : 0u);
  b |= (v3.z ? 0x4000u : 0u); b |= (v3.w ? 0x8000u : 0u);
  return b;
}

// ---- fused prep (r15 verbatim): blocks 0..255 g-GEMM, 256..2303 pack ----
__launch_bounds__(256)
__global__ void k_prep(const int* __restrict__ adj, const float* __restrict__ hmat,
                       const float* __restrict__ W, const float* __restrict__ aw,
                       ushort* __restrict__ bmb, short* __restrict__ gT,
                       float* __restrict__ slT2, float* __restrict__ srT2,
                       uint32_t* __restrict__ srmax2){
  __shared__ float hsT[64][68];
  __shared__ float wsT[64][68];
  __shared__ float smax_l[16];
  int bid = blockIdx.x;
  int t   = threadIdx.x;

  if (bid >= 256){
    int row = (bid - 256) * 2;
    const int* p0 = adj + (size_t)row*NN + t*16;
    const int* p1 = p0 + NN;
    int4 a0 = *(const int4*)(p0);      int4 a1 = *(const int4*)(p0 + 4);
    int4 a2 = *(const int4*)(p0 + 8);  int4 a3 = *(const int4*)(p0 + 12);
    int4 b0 = *(const int4*)(p1);      int4 b1 = *(const int4*)(p1 + 4);
    int4 b2 = *(const int4*)(p1 + 8);  int4 b3 = *(const int4*)(p1 + 12);
    bmb[(size_t)row*256 + t]       = (ushort)pack16(a0, a1, a2, a3);
    bmb[(size_t)(row + 1)*256 + t] = (ushort)pack16(b0, b1, b2, b3);
    return;
  }

  int tx = t & 15, ty = t >> 4;
  int r0 = (bid & 63) * 64;
  int cb = bid >> 6;
  int c0 = cb * 64;
  float acc[4][4] = {};

  for (int k0 = 0; k0 < INF_; k0 += 64){
    int row = t >> 2, kc = (t & 3) * 16;
    #pragma unroll
    for (int u = 0; u < 4; u++){
      float4 v = *(const float4*)&hmat[(r0 + row)*INF_ + k0 + kc + 4*u];
      hsT[kc + 4*u + 0][row] = v.x;
      hsT[kc + 4*u + 1][row] = v.y;
      hsT[kc + 4*u + 2][row] = v.z;
      hsT[kc + 4*u + 3][row] = v.w;
    }
    #pragma unroll
    for (int u = 0; u < 4; u++){
      float4 v = *(const float4*)&W[(c0 + row)*INF_ + k0 + kc + 4*u];
      wsT[kc + 4*u + 0][row] = v.x;
      wsT[kc + 4*u + 1][row] = v.y;
      wsT[kc + 4*u + 2][row] = v.z;
      wsT[kc + 4*u + 3][row] = v.w;
    }
    __syncthreads();
    #pragma unroll 8
    for (int k = 0; k < 64; k++){
      float4 hv = *(const float4*)&hsT[k][ty*4];
      float4 wv = *(const float4*)&wsT[k][tx*4];
      float ha[4] = {hv.x, hv.y, hv.z, hv.w};
      float wa[4] = {wv.x, wv.y, wv.z, wv.w};
      #pragma unroll
      for (int a_ = 0; a_ < 4; a_++)
        #pragma unroll
        for (int b_ = 0; b_ < 4; b_++)
          acc[a_][b_] = fmaf(ha[a_], wa[b_], acc[a_][b_]);
    }
    __syncthreads();
  }

  float alv[4], arv[4];
  #pragma unroll
  for (int j = 0; j < 4; j++){ alv[j] = aw[tx*4 + j]; arv[j] = aw[64 + tx*4 + j]; }
  float rmax = -3.4e38f;
  #pragma unroll
  for (int qi = 0; qi < 4; qi++){
    int r = r0 + ty*4 + qi;
    float slp = 0.f, srp = 0.f;
    #pragma unroll
    for (int j = 0; j < 4; j++){
      slp = fmaf(acc[qi][j], alv[j], slp);
      srp = fmaf(acc[qi][j], arv[j], srp);
    }
    #pragma unroll
    for (int m = 1; m < 16; m <<= 1){
      slp += __shfl_xor(slp, m, 64);
      srp += __shfl_xor(srp, m, 64);
    }
    if (tx == 0){
      slT2[(size_t)cb*NN + r] = slp * L2E;
      srT2[(size_t)cb*NN + r] = srp * L2E;
      rmax = fmaxf(rmax, srp * L2E);
    }
  }
  if (tx == 0) smax_l[ty] = rmax;

  float* T = (float*)hsT;
  #pragma unroll
  for (int qi = 0; qi < 4; qi++)
    #pragma unroll
    for (int j = 0; j < 4; j++)
      T[(tx*4 + j)*65 + ty*4 + qi] = acc[qi][j];
  __syncthreads();
  if (t == 0){
    float m = smax_l[0];
    #pragma unroll
    for (int i = 1; i < 16; i++) m = fmaxf(m, smax_l[i]);
    atomicMax(srmax2 + cb, ford(m));
  }
  int c = t >> 2, rb = (t & 3) * 16;
  ushort u16[16];
  #pragma unroll
  for (int v = 0; v < 16; v++) u16[v] = bf16u(T[c*65 + rb + v]);
  *(uint4*)&gT[(size_t)(c0 + c)*NN + r0 + rb]     = *(uint4*)&u16[0];
  *(uint4*)&gT[(size_t)(c0 + c)*NN + r0 + rb + 8] = *(uint4*)&u16[8];
}

// ---- fused masked-softmax attention: transcendental-free hot loop.
//      LDS holds pe=exp2(sr-srmax), qe=exp2(NEG*(sr-srmax)) as packed bf16
//      pairs. Branch select = u16 threshold compare (pe >= exp2(-x)) via
//      packed int16 ops; two accumulator sets combined by row scales E1,E2
//      in the epilogue. Structure otherwise = r15 champion. ----
__launch_bounds__(256, 3)
__global__ void k_attn(const short* __restrict__ gT, const float* __restrict__ slT2,
                       const float* __restrict__ srT2, const uint32_t* __restrict__ srmax2,
                       const uint32_t* __restrict__ bm,
                       __hip_bfloat16* __restrict__ num_p, float* __restrict__ den_p){
  __shared__ uint32_t pelds[4][256];    // [head][j-pair]: packed bf16 {pe0,pe1}
  __shared__ uint32_t qelds[4][256];    // [head][j-pair]: packed bf16 {qe0,qe1}
  __shared__ uint32_t bmlds[32 * 18];   // [row][word] stride 18 -> conflict-free
  __shared__ float    e1t[4][32];       // row scale exp2(x - lrelu(x))
  __shared__ float    e2t[4][32];       // row scale exp2(NEG*x - lrelu(x))
  int t  = threadIdx.x;
  int h  = t >> 6, l = t & 63;
  int lr = l & 15, lg = l >> 4;
  int i0 = blockIdx.x * BI;
  int jb = blockIdx.y * NJ;
  int js = blockIdx.y;

  float srmaxh = funord(srmax2[h]);

  // stage pe/qe tables (wave h -> head h's 512 j) + bitmask tile
  {
    int jj = l * 8;
    float4 v0 = *(const float4*)&srT2[(size_t)h*NN + jb + jj];
    float4 v1 = *(const float4*)&srT2[(size_t)h*NN + jb + jj + 4];
    float sv[8] = {v0.x, v0.y, v0.z, v0.w, v1.x, v1.y, v1.z, v1.w};
    uint32_t pp[4], qq[4];
    #pragma unroll
    for (int q = 0; q < 4; q++){
      float s0 = sv[2*q]     - srmaxh;
      float s1 = sv[2*q + 1] - srmaxh;
      uint32_t p0 = __float_as_uint(__builtin_amdgcn_exp2f(s0)) + 0x8000u;
      uint32_t p1 = __float_as_uint(__builtin_amdgcn_exp2f(s1)) + 0x8000u;
      pp[q] = __builtin_amdgcn_perm(p1, p0, 0x07060302u);
      uint32_t q0 = __float_as_uint(__builtin_amdgcn_exp2f(NEG * s0)) + 0x8000u;
      uint32_t q1 = __float_as_uint(__builtin_amdgcn_exp2f(NEG * s1)) + 0x8000u;
      qq[q] = __builtin_amdgcn_perm(q1, q0, 0x07060302u);
    }
    *(uint4*)&pelds[h][l*4] = *(uint4*)pp;
    *(uint4*)&qelds[h][l*4] = *(uint4*)qq;
    int r = t >> 3, wd = (t & 7) * 2;
    uint2 v = *(const uint2*)&bm[(size_t)(i0 + r)*128 + (jb >> 5) + wd];
    bmlds[r*18 + wd]     = v.x;
    bmlds[r*18 + wd + 1] = v.y;
  }
  // row-scale tables (one thread per (head,row))
  if (t < 128){
    int hh = t >> 5, row = t & 31;
    float xr = slT2[(size_t)hh*NN + i0 + row] + funord(srmax2[hh]);
    float mshr = fmaxf(xr, NEG * xr);
    e1t[hh][row] = __builtin_amdgcn_exp2f(xr - mshr);
    e2t[hh][row] = __builtin_amdgcn_exp2f(fmaf(NEG, xr, -mshr));
  }
  // per-thread branch thresholds (rows m*16+lr)
  uint32_t Pt2[2];
  #pragma unroll
  for (int m = 0; m < 2; m++){
    float slv = slT2[(size_t)h*NN + i0 + m*16 + lr];
    float x   = slv + srmaxh;
    uint32_t pt16 = (__float_as_uint(__builtin_amdgcn_exp2f(-x)) + 0x8000u) >> 16;
    Pt2[m] = pt16 | (pt16 << 16);
  }
  __syncthreads();

  f32x4 acc1[2][4] = {}, acc2[2][4] = {};
  f32x4 dacc1[2] = {}, dacc2[2] = {};
  bf16x8 ones;
  #pragma unroll
  for (int q = 0; q < 8; q++) ones[q] = (short)0x3F80;

  const short* gTh = gT + (size_t)h*HID*NN;
  const short* bp[4];
  #pragma unroll
  for (int n = 0; n < 4; n++)
    bp[n] = gTh + (size_t)(n*16 + lr)*NN + jb + lg*8;

  bf16x8 Bb[2][4];
  #pragma unroll
  for (int n = 0; n < 4; n++){
    Bb[0][n] = *(const bf16x8*)(bp[n]);
    Bb[1][n] = *(const bf16x8*)(bp[n] + 32);
  }

  // step-0 LDS operands
  uint4 pec = *(const uint4*)&pelds[h][lg*4];
  uint4 qec = *(const uint4*)&qelds[h][lg*4];
  uint32_t w0c = bmlds[lr*18];
  uint32_t w1c = bmlds[(16 + lr)*18];

  #pragma unroll
  for (int s = 0; s < 16; s++){
    // prefetch next step's LDS operands
    uint4 pen = pec, qen = qec;
    uint32_t w0n = 0, w1n = 0;
    if (s < 15){
      pen = *(const uint4*)&pelds[h][(s+1)*16 + lg*4];
      qen = *(const uint4*)&qelds[h][(s+1)*16 + lg*4];
      w0n = bmlds[lr*18 + s + 1];
      w1n = bmlds[(16 + lr)*18 + s + 1];
    }
    uint32_t pea[4] = {pec.x, pec.y, pec.z, pec.w};
    uint32_t qea[4] = {qec.x, qec.y, qec.z, qec.w};

    bf16x8 A1[2], A2[2];
    #pragma unroll
    for (int m = 0; m < 2; m++){
      uint32_t word = (m ? w1c : w0c) >> (lg*8);
      uint32_t a1p[4], a2p[4];
      #pragma unroll
      for (int p = 0; p < 4; p++){
        int b0 = (int)(word << (31 - 2*p)) >> 31;
        int b1 = (int)(word << (30 - 2*p)) >> 31;
        uint32_t adjM = __builtin_amdgcn_perm((uint32_t)b1, (uint32_t)b0, 0x05040100u);
        // threshold select: per-u16-lane (pe - Pt) sign -> negative-branch mask
        u16x2 pv = *(u16x2*)&pea[p];
        u16x2 tv = pv - *(u16x2*)&Pt2[m];
        s16x2 cm = (*(s16x2*)&tv) >> 15;          // 0xFFFF where pe < Pt
        uint32_t cmn = *(uint32_t*)&cm;
        uint32_t padj = pea[p] & adjM;
        uint32_t qadj = qea[p] & adjM;
        a1p[p] = padj & ~cmn;                      // positive branch entries
        a2p[p] = qadj &  cmn;                      // negative branch entries
      }
      A1[m] = *(bf16x8*)a1p;
      A2[m] = *(bf16x8*)a2p;
    }

    __builtin_amdgcn_s_setprio(1);
    #pragma unroll
    for (int m = 0; m < 2; m++){
      dacc1[m] = __builtin_amdgcn_mfma_f32_16x16x32_bf16(A1[m], ones, dacc1[m], 0, 0, 0);
      dacc2[m] = __builtin_amdgcn_mfma_f32_16x16x32_bf16(A2[m], ones, dacc2[m], 0, 0, 0);
      #pragma unroll
      for (int n = 0; n < 4; n++){
        acc1[m][n] = __builtin_amdgcn_mfma_f32_16x16x32_bf16(A1[m], Bb[s & 1][n], acc1[m][n], 0, 0, 0);
        acc2[m][n] = __builtin_amdgcn_mfma_f32_16x16x32_bf16(A2[m], Bb[s & 1][n], acc2[m][n], 0, 0, 0);
      }
    }
    __builtin_amdgcn_s_setprio(0);

    if (s + 2 < 16){
      #pragma unroll
      for (int n = 0; n < 4; n++)
        Bb[s & 1][n] = *(const bf16x8*)(bp[n] + (s + 2)*32);
    }
    pec = pen; qec = qen; w0c = w0n; w1c = w1n;
  }

  // epilogue: combine branches with row scales; write num/den partials
  #pragma unroll
  for (int m = 0; m < 2; m++){
    float e1v[4], e2v[4];
    #pragma unroll
    for (int r = 0; r < 4; r++){
      e1v[r] = e1t[h][m*16 + lg*4 + r];
      e2v[r] = e2t[h][m*16 + lg*4 + r];
    }
    #pragma unroll
    for (int n = 0; n < 4; n++)
      #pragma unroll
      for (int r = 0; r < 4; r++){
        float f = fmaf(e1v[r], acc1[m][n][r], e2v[r] * acc2[m][n][r]);
        num_p[((size_t)js*NN + i0 + m*16 + lg*4 + r)*OUTC + h*HID + n*16 + lr] =
            __float2bfloat16(f);
      }
    if (lr == 0)
      #pragma unroll
      for (int r = 0; r < 4; r++)
        den_p[((size_t)js*4 + h)*NN + i0 + m*16 + lg*4 + r] =
            fmaf(e1v[r], dacc1[m][r], e2v[r] * dacc2[m][r]);
  }
}

// ---- combine partials: out = sum(num)/sum(den), 2 cols/thread ----
__global__ void k_comb(const __hip_bfloat16* __restrict__ num_p,
                       const float* __restrict__ den_p, float* __restrict__ out){
  int t  = threadIdx.x;
  int r  = blockIdx.x*2 + (t >> 7);
  int c2 = (t & 127) * 2;
  int h  = c2 >> 6;
  float s0 = 0.f, s1 = 0.f, d = 0.f;
  #pragma unroll
  for (int js = 0; js < JSPLIT; js++){
    uint32_t u = *(const uint32_t*)&num_p[((size_t)js*NN + r)*OUTC + c2];
    s0 += __uint_as_float(u << 16);
    s1 += __uint_as_float(u & 0xffff0000u);
  }
  #pragma unroll
  for (int js = 0; js < JSPLIT; js++)
    d += den_p[((size_t)js*4 + h)*NN + r];
  float inv = 1.0f / d;
  *(float2*)&out[(size_t)r*OUTC + c2] = make_float2(s0*inv, s1*inv);
}

extern "C" void kernel_launch(void* const* d_in, const int* in_sizes, int n_in,
                              void* d_out, int out_size, void* d_ws, size_t ws_size,
                              hipStream_t stream){
  const float* hmat = (const float*)d_in[0];
  const int*   adj  = (const int*)d_in[1];     // int32 layout confirmed in r1
  const float* W    = (const float*)d_in[2];
  const float* aw   = (const float*)d_in[3];
  float* out = (float*)d_out;
  char*  ws  = (char*)d_ws;

  // ws layout (bytes), total ~21.6 MB (r15 proven)
  uint32_t* srmax2 = (uint32_t*)(ws);                      // 64 B
  float*    slT2   = (float*)(ws + 1024);                  // 64 KB
  float*    srT2   = (float*)(ws + 66560);                 // 64 KB
  short*    gT     = (short*)(ws + 132096);                // 2 MB   [256][4096] bf16
  float*    den_p  = (float*)(ws + 2229248);               // 512 KB [8][4][4096]
  __hip_bfloat16* num_p = (__hip_bfloat16*)(ws + 2753536); // 16.75 MB [8][4096][256]
  uint32_t* bmask  = (uint32_t*)(ws + 19530752);           // 2 MB   [4096][128] (byte-packed)

  hipMemsetAsync(ws, 0, 64, stream);   // srmax2 init
  hipLaunchKernelGGL(k_prep, dim3(2304), dim3(256), 0, stream,
                     adj, hmat, W, aw, (ushort*)bmask, gT, slT2, srT2, srmax2);
  hipLaunchKernelGGL(k_attn, dim3(NN/BI, JSPLIT), dim3(256), 0, stream,
                     gT, slT2, srT2, srmax2, bmask, num_p, den_p);
  hipLaunchKernelGGL(k_comb, dim3(NN/2), dim3(256), 0, stream, num_p, den_p, out);
}

// Round 19
// 59.431 us; speedup vs baseline: 4.1824x; 1.1447x over previous
//
#include <hip/hip_runtime.h>
#include <hip/hip_bf16.h>
#include <stdint.h>

#define NN    4096
#define INF_  256
#define HEADS 4
#define HID   64
#define OUTC  256
#define NEG   0.2f
#define L2E   1.44269504f

#define BI     64               // i-rows per block (2 i-halves of 32)
#define JSPLIT 8
#define NJ     (NN / JSPLIT)

typedef short bf16x8 __attribute__((ext_vector_type(8)));
typedef float f32x4  __attribute__((ext_vector_type(4)));

// ---- float <-> order-preserving uint encoding (for atomicMax on f32) ----
__device__ __forceinline__ uint32_t ford(float x){
  uint32_t u = __float_as_uint(x);
  return (u & 0x80000000u) ? ~u : (u | 0x80000000u);
}
__device__ __forceinline__ float funord(uint32_t e){
  uint32_t u = (e & 0x80000000u) ? (e & 0x7fffffffu) : ~e;
  return __uint_as_float(u);
}
__device__ __forceinline__ ushort bf16u(float f){
  __hip_bfloat16 b = __float2bfloat16(f);
  return *reinterpret_cast<ushort*>(&b);
}

__device__ __forceinline__ uint32_t pack16(int4 v0, int4 v1, int4 v2, int4 v3){
  uint32_t b = 0;
  b |= (v0.x ? 0x0001u : 0u); b |= (v0.y ? 0x0002u : 0u);
  b |= (v0.z ? 0x0004u : 0u); b |= (v0.w ? 0x0008u : 0u);
  b |= (v1.x ? 0x0010u : 0u); b |= (v1.y ? 0x0020u : 0u);
  b |= (v1.z ? 0x0040u : 0u); b |= (v1.w ? 0x0080u : 0u);
  b |= (v2.x ? 0x0100u : 0u); b |= (v2.y ? 0x0200u : 0u);
  b |= (v2.z ? 0x0400u : 0u); b |= (v2.w ? 0x0800u : 0u);
  b |= (v3.x ? 0x1000u : 0u); b |= (v3.y ? 0x2000u : 0u);
  b |= (v3.z ? 0x4000u : 0u); b |= (v3.w ? 0x8000u : 0u);
  return b;
}

// ---- fused prep (r15 verbatim): blocks 0..255 g-GEMM, 256..2303 pack ----
__launch_bounds__(256)
__global__ void k_prep(const int* __restrict__ adj, const float* __restrict__ hmat,
                       const float* __restrict__ W, const float* __restrict__ aw,
                       ushort* __restrict__ bmb, short* __restrict__ gT,
                       float* __restrict__ slT2, float* __restrict__ srT2,
                       uint32_t* __restrict__ srmax2){
  __shared__ float hsT[64][68];
  __shared__ float wsT[64][68];
  __shared__ float smax_l[16];
  int bid = blockIdx.x;
  int t   = threadIdx.x;

  if (bid >= 256){
    int row = (bid - 256) * 2;
    const int* p0 = adj + (size_t)row*NN + t*16;
    const int* p1 = p0 + NN;
    int4 a0 = *(const int4*)(p0);      int4 a1 = *(const int4*)(p0 + 4);
    int4 a2 = *(const int4*)(p0 + 8);  int4 a3 = *(const int4*)(p0 + 12);
    int4 b0 = *(const int4*)(p1);      int4 b1 = *(const int4*)(p1 + 4);
    int4 b2 = *(const int4*)(p1 + 8);  int4 b3 = *(const int4*)(p1 + 12);
    bmb[(size_t)row*256 + t]       = (ushort)pack16(a0, a1, a2, a3);
    bmb[(size_t)(row + 1)*256 + t] = (ushort)pack16(b0, b1, b2, b3);
    return;
  }

  int tx = t & 15, ty = t >> 4;
  int r0 = (bid & 63) * 64;
  int cb = bid >> 6;
  int c0 = cb * 64;
  float acc[4][4] = {};

  for (int k0 = 0; k0 < INF_; k0 += 64){
    int row = t >> 2, kc = (t & 3) * 16;
    #pragma unroll
    for (int u = 0; u < 4; u++){
      float4 v = *(const float4*)&hmat[(r0 + row)*INF_ + k0 + kc + 4*u];
      hsT[kc + 4*u + 0][row] = v.x;
      hsT[kc + 4*u + 1][row] = v.y;
      hsT[kc + 4*u + 2][row] = v.z;
      hsT[kc + 4*u + 3][row] = v.w;
    }
    #pragma unroll
    for (int u = 0; u < 4; u++){
      float4 v = *(const float4*)&W[(c0 + row)*INF_ + k0 + kc + 4*u];
      wsT[kc + 4*u + 0][row] = v.x;
      wsT[kc + 4*u + 1][row] = v.y;
      wsT[kc + 4*u + 2][row] = v.z;
      wsT[kc + 4*u + 3][row] = v.w;
    }
    __syncthreads();
    #pragma unroll 8
    for (int k = 0; k < 64; k++){
      float4 hv = *(const float4*)&hsT[k][ty*4];
      float4 wv = *(const float4*)&wsT[k][tx*4];
      float ha[4] = {hv.x, hv.y, hv.z, hv.w};
      float wa[4] = {wv.x, wv.y, wv.z, wv.w};
      #pragma unroll
      for (int a_ = 0; a_ < 4; a_++)
        #pragma unroll
        for (int b_ = 0; b_ < 4; b_++)
          acc[a_][b_] = fmaf(ha[a_], wa[b_], acc[a_][b_]);
    }
    __syncthreads();
  }

  float alv[4], arv[4];
  #pragma unroll
  for (int j = 0; j < 4; j++){ alv[j] = aw[tx*4 + j]; arv[j] = aw[64 + tx*4 + j]; }
  float rmax = -3.4e38f;
  #pragma unroll
  for (int qi = 0; qi < 4; qi++){
    int r = r0 + ty*4 + qi;
    float slp = 0.f, srp = 0.f;
    #pragma unroll
    for (int j = 0; j < 4; j++){
      slp = fmaf(acc[qi][j], alv[j], slp);
      srp = fmaf(acc[qi][j], arv[j], srp);
    }
    #pragma unroll
    for (int m = 1; m < 16; m <<= 1){
      slp += __shfl_xor(slp, m, 64);
      srp += __shfl_xor(srp, m, 64);
    }
    if (tx == 0){
      slT2[(size_t)cb*NN + r] = slp * L2E;
      srT2[(size_t)cb*NN + r] = srp * L2E;
      rmax = fmaxf(rmax, srp * L2E);
    }
  }
  if (tx == 0) smax_l[ty] = rmax;

  float* T = (float*)hsT;
  #pragma unroll
  for (int qi = 0; qi < 4; qi++)
    #pragma unroll
    for (int j = 0; j < 4; j++)
      T[(tx*4 + j)*65 + ty*4 + qi] = acc[qi][j];
  __syncthreads();
  if (t == 0){
    float m = smax_l[0];
    #pragma unroll
    for (int i = 1; i < 16; i++) m = fmaxf(m, smax_l[i]);
    atomicMax(srmax2 + cb, ford(m));
  }
  int c = t >> 2, rb = (t & 3) * 16;
  ushort u16[16];
  #pragma unroll
  for (int v = 0; v < 16; v++) u16[v] = bf16u(T[c*65 + rb + v]);
  *(uint4*)&gT[(size_t)(c0 + c)*NN + r0 + rb]     = *(uint4*)&u16[0];
  *(uint4*)&gT[(size_t)(c0 + c)*NN + r0 + rb + 8] = *(uint4*)&u16[8];
}

// ---- fused masked-softmax attention: 8 waves = 4 heads x 2 i-halves (BI=64).
//      B staged per-step into double-buffered LDS (80B row stride, <=2-way
//      banks); per-wave inner loop = r15 champion (exp2 A-build, m=2,
//      ones-MFMA den, v_perm pack, setprio). One barrier per step. ----
__launch_bounds__(512)
__global__ void k_attn(const short* __restrict__ gT, const float* __restrict__ slT2,
                       const float* __restrict__ srT2, const uint32_t* __restrict__ srmax2,
                       const uint32_t* __restrict__ bm,
                       __hip_bfloat16* __restrict__ num_p, float* __restrict__ den_p){
  __shared__ float    srs[4][512];         // [head][j - jb]
  __shared__ uint32_t bmlds[64 * 18];      // [row][word]
  __shared__ short    Bst[2][4*64*40];     // [buf][head][row][40]  (32 used + 8 pad)
  int t  = threadIdx.x;
  int w  = t >> 6, l = t & 63;
  int h  = w & 3, ihalf = w >> 2;
  int lr = l & 15, lg = l >> 4;
  int ib = blockIdx.x * BI;
  int i0 = ib + ihalf * 32;
  int jb = blockIdx.y * NJ;
  int js = blockIdx.y;

  // staging thread identity for B tiles
  int sh  = t >> 7;            // head 0..3
  int srw = (t >> 1) & 63;     // row 0..63
  int spt = t & 1;             // 16-short half 0..1
  const short* gsrc = gT + (size_t)(sh*HID + srw)*NN + jb + spt*16;
  short* ldst0 = &Bst[0][sh*2560 + srw*40 + spt*16];
  short* ldst1 = &Bst[1][sh*2560 + srw*40 + spt*16];

  // stage sr slice + bitmask tile (512 threads, one op each)
  {
    int hh = t >> 7, jj = (t & 127) * 4;
    *(float4*)&srs[hh][jj] = *(const float4*)&srT2[(size_t)hh*NN + jb + jj];
    int r = t >> 3, wd = (t & 7) * 2;
    uint2 v = *(const uint2*)&bm[(size_t)(ib + r)*128 + (jb >> 5) + wd];
    bmlds[r*18 + wd]     = v.x;
    bmlds[r*18 + wd + 1] = v.y;
  }

  float srmaxh = funord(srmax2[h]);
  float d1[2], cc[2];
  #pragma unroll
  for (int m = 0; m < 2; m++){
    float slv = slT2[(size_t)h*NN + i0 + m*16 + lr];
    float xx  = slv + srmaxh;
    float msh = fmaxf(xx, NEG * xx);
    d1[m] = slv - msh;              // z = d1 + sr
    cc[m] = (NEG - 1.0f) * msh;     // neg branch: NEG*z + cc
  }

  // prologue: stage step 0 into buf 0
  {
    uint4 g0 = *(const uint4*)(gsrc);
    uint4 g1 = *(const uint4*)(gsrc + 8);
    *(uint4*)(ldst0)     = g0;
    *(uint4*)(ldst0 + 8) = g1;
  }
  __syncthreads();

  f32x4 acc[2][4] = {};
  f32x4 dacc[2]   = {};
  bf16x8 ones;
  #pragma unroll
  for (int q = 0; q < 8; q++) ones[q] = (short)0x3F80;

  // B-frag LDS pointers (byte-aligned b128): head h, row n*16+lr, cols lg*8
  const short* brd0 = &Bst[0][h*2560 + lr*40 + lg*8];
  const short* brd1 = &Bst[1][h*2560 + lr*40 + lg*8];

  bf16x8 Bb[4];
  #pragma unroll
  for (int n = 0; n < 4; n++)
    Bb[n] = *(const bf16x8*)(brd0 + n*640);   // 16 rows * 40 shorts

  int rowl0 = (ihalf*32 + lr) * 18;
  int rowl1 = (ihalf*32 + 16 + lr) * 18;
  float4 s0c = *(const float4*)&srs[h][lg*8];
  float4 s1c = *(const float4*)&srs[h][lg*8 + 4];
  uint32_t w0c = bmlds[rowl0];
  uint32_t w1c = bmlds[rowl1];

  #pragma unroll
  for (int s = 0; s < 16; s++){
    // issue next step's global loads early
    uint4 g0, g1;
    if (s < 15){
      g0 = *(const uint4*)(gsrc + (s+1)*32);
      g1 = *(const uint4*)(gsrc + (s+1)*32 + 8);
    }
    // prefetch next step's sr/bm operands
    float4 s0n = s0c, s1n = s1c;
    uint32_t w0n = 0, w1n = 0;
    if (s < 15){
      s0n = *(const float4*)&srs[h][(s+1)*32 + lg*8];
      s1n = *(const float4*)&srs[h][(s+1)*32 + lg*8 + 4];
      w0n = bmlds[rowl0 + s + 1];
      w1n = bmlds[rowl1 + s + 1];
    }
    float sr8[8] = {s0c.x, s0c.y, s0c.z, s0c.w, s1c.x, s1c.y, s1c.z, s1c.w};

    bf16x8 A[2];
    #pragma unroll
    for (int m = 0; m < 2; m++){
      uint32_t word = (m ? w1c : w0c) >> (lg*8);
      uint32_t pk[4];
      #pragma unroll
      for (int p = 0; p < 4; p++){
        float z0 = d1[m] + sr8[2*p];
        float z1 = d1[m] + sr8[2*p + 1];
        float v0 = __builtin_amdgcn_exp2f(fmaxf(z0, fmaf(NEG, z0, cc[m])));
        float v1 = __builtin_amdgcn_exp2f(fmaxf(z1, fmaf(NEG, z1, cc[m])));
        int m0 = (int)(word << (31 - 2*p)) >> 31;
        int m1 = (int)(word << (30 - 2*p)) >> 31;
        v0 = __uint_as_float(__float_as_uint(v0) & (uint32_t)m0);
        v1 = __uint_as_float(__float_as_uint(v1) & (uint32_t)m1);
        uint32_t u0 = __float_as_uint(v0) + 0x8000u;
        uint32_t u1 = __float_as_uint(v1) + 0x8000u;
        pk[p] = __builtin_amdgcn_perm(u1, u0, 0x07060302u);
      }
      A[m] = *(bf16x8*)pk;
    }

    __builtin_amdgcn_s_setprio(1);
    dacc[0] = __builtin_amdgcn_mfma_f32_16x16x32_bf16(A[0], ones, dacc[0], 0, 0, 0);
    #pragma unroll
    for (int n = 0; n < 4; n++)
      acc[0][n] = __builtin_amdgcn_mfma_f32_16x16x32_bf16(A[0], Bb[n], acc[0][n], 0, 0, 0);
    dacc[1] = __builtin_amdgcn_mfma_f32_16x16x32_bf16(A[1], ones, dacc[1], 0, 0, 0);
    #pragma unroll
    for (int n = 0; n < 4; n++)
      acc[1][n] = __builtin_amdgcn_mfma_f32_16x16x32_bf16(A[1], Bb[n], acc[1][n], 0, 0, 0);
    __builtin_amdgcn_s_setprio(0);

    if (s < 15){
      // write next step's B into the other buffer, then sync, then read frags
      short* dst = ((s+1) & 1) ? ldst1 : ldst0;
      *(uint4*)(dst)     = g0;
      *(uint4*)(dst + 8) = g1;
      __syncthreads();
      const short* rd = ((s+1) & 1) ? brd1 : brd0;
      #pragma unroll
      for (int n = 0; n < 4; n++)
        Bb[n] = *(const bf16x8*)(rd + n*640);
    }
    s0c = s0n; s1c = s1n; w0c = w0n; w1c = w1n;
  }

  // num partials (bf16): row = i0+m*16+lg*4+r, col = h*64+n*16+lr
  #pragma unroll
  for (int m = 0; m < 2; m++)
    #pragma unroll
    for (int n = 0; n < 4; n++)
      #pragma unroll
      for (int r = 0; r < 4; r++)
        num_p[((size_t)js*NN + i0 + m*16 + lg*4 + r)*OUTC + h*HID + n*16 + lr] =
            __float2bfloat16(acc[m][n][r]);

  // den partials from ones-MFMA: row m*16+lg*4+r value sits in dacc[m][r] (any lr)
  if (lr == 0)
    #pragma unroll
    for (int m = 0; m < 2; m++)
      #pragma unroll
      for (int r = 0; r < 4; r++)
        den_p[((size_t)js*4 + h)*NN + i0 + m*16 + lg*4 + r] = dacc[m][r];
}

// ---- combine partials: out = sum(num)/sum(den), 2 cols/thread ----
__global__ void k_comb(const __hip_bfloat16* __restrict__ num_p,
                       const float* __restrict__ den_p, float* __restrict__ out){
  int t  = threadIdx.x;
  int r  = blockIdx.x*2 + (t >> 7);
  int c2 = (t & 127) * 2;
  int h  = c2 >> 6;
  float s0 = 0.f, s1 = 0.f, d = 0.f;
  #pragma unroll
  for (int js = 0; js < JSPLIT; js++){
    uint32_t u = *(const uint32_t*)&num_p[((size_t)js*NN + r)*OUTC + c2];
    s0 += __uint_as_float(u << 16);
    s1 += __uint_as_float(u & 0xffff0000u);
  }
  #pragma unroll
  for (int js = 0; js < JSPLIT; js++)
    d += den_p[((size_t)js*4 + h)*NN + r];
  float inv = 1.0f / d;
  *(float2*)&out[(size_t)r*OUTC + c2] = make_float2(s0*inv, s1*inv);
}

extern "C" void kernel_launch(void* const* d_in, const int* in_sizes, int n_in,
                              void* d_out, int out_size, void* d_ws, size_t ws_size,
                              hipStream_t stream){
  const float* hmat = (const float*)d_in[0];
  const int*   adj  = (const int*)d_in[1];     // int32 layout confirmed in r1
  const float* W    = (const float*)d_in[2];
  const float* aw   = (const float*)d_in[3];
  float* out = (float*)d_out;
  char*  ws  = (char*)d_ws;

  // ws layout (bytes), total ~21.6 MB (r15 proven)
  uint32_t* srmax2 = (uint32_t*)(ws);                      // 64 B
  float*    slT2   = (float*)(ws + 1024);                  // 64 KB
  float*    srT2   = (float*)(ws + 66560);                 // 64 KB
  short*    gT     = (short*)(ws + 132096);                // 2 MB   [256][4096] bf16
  float*    den_p  = (float*)(ws + 2229248);               // 512 KB [8][4][4096]
  __hip_bfloat16* num_p = (__hip_bfloat16*)(ws + 2753536); // 16.75 MB [8][4096][256]
  uint32_t* bmask  = (uint32_t*)(ws + 19530752);           // 2 MB   [4096][128] (byte-packed)

  hipMemsetAsync(ws, 0, 64, stream);   // srmax2 init
  hipLaunchKernelGGL(k_prep, dim3(2304), dim3(256), 0, stream,
                     adj, hmat, W, aw, (ushort*)bmask, gT, slT2, srT2, srmax2);
  hipLaunchKernelGGL(k_attn, dim3(NN/BI, JSPLIT), dim3(512), 0, stream,
                     gT, slT2, srT2, srmax2, bmask, num_p, den_p);
  hipLaunchKernelGGL(k_comb, dim3(NN/2), dim3(256), 0, stream, num_p, den_p, out);
}

// Round 20
// 56.239 us; speedup vs baseline: 4.4198x; 1.0568x over previous
//
#include <hip/hip_runtime.h>
#include <hip/hip_bf16.h>
#include <stdint.h>

#define NN    4096
#define INF_  256
#define HEADS 4
#define HID   64
#define OUTC  256
#define NEG   0.2f
#define L2E   1.44269504f

#define BI     64               // i-rows per block (2 i-halves of 32)
#define JSPLIT 8
#define NJ     (NN / JSPLIT)

typedef short bf16x8 __attribute__((ext_vector_type(8)));
typedef float f32x4  __attribute__((ext_vector_type(4)));

// ---- float <-> order-preserving uint encoding (for atomicMax on f32) ----
__device__ __forceinline__ uint32_t ford(float x){
  uint32_t u = __float_as_uint(x);
  return (u & 0x80000000u) ? ~u : (u | 0x80000000u);
}
__device__ __forceinline__ float funord(uint32_t e){
  uint32_t u = (e & 0x80000000u) ? (e & 0x7fffffffu) : ~e;
  return __uint_as_float(u);
}
__device__ __forceinline__ ushort bf16u(float f){
  __hip_bfloat16 b = __float2bfloat16(f);
  return *reinterpret_cast<ushort*>(&b);
}

__device__ __forceinline__ uint32_t pack16(int4 v0, int4 v1, int4 v2, int4 v3){
  uint32_t b = 0;
  b |= (v0.x ? 0x0001u : 0u); b |= (v0.y ? 0x0002u : 0u);
  b |= (v0.z ? 0x0004u : 0u); b |= (v0.w ? 0x0008u : 0u);
  b |= (v1.x ? 0x0010u : 0u); b |= (v1.y ? 0x0020u : 0u);
  b |= (v1.z ? 0x0040u : 0u); b |= (v1.w ? 0x0080u : 0u);
  b |= (v2.x ? 0x0100u : 0u); b |= (v2.y ? 0x0200u : 0u);
  b |= (v2.z ? 0x0400u : 0u); b |= (v2.w ? 0x0800u : 0u);
  b |= (v3.x ? 0x1000u : 0u); b |= (v3.y ? 0x2000u : 0u);
  b |= (v3.z ? 0x4000u : 0u); b |= (v3.w ? 0x8000u : 0u);
  return b;
}

// ---- fused prep (r15 verbatim): blocks 0..255 g-GEMM, 256..2303 pack ----
__launch_bounds__(256)
__global__ void k_prep(const int* __restrict__ adj, const float* __restrict__ hmat,
                       const float* __restrict__ W, const float* __restrict__ aw,
                       ushort* __restrict__ bmb, short* __restrict__ gT,
                       float* __restrict__ slT2, float* __restrict__ srT2,
                       uint32_t* __restrict__ srmax2){
  __shared__ float hsT[64][68];
  __shared__ float wsT[64][68];
  __shared__ float smax_l[16];
  int bid = blockIdx.x;
  int t   = threadIdx.x;

  if (bid >= 256){
    int row = (bid - 256) * 2;
    const int* p0 = adj + (size_t)row*NN + t*16;
    const int* p1 = p0 + NN;
    int4 a0 = *(const int4*)(p0);      int4 a1 = *(const int4*)(p0 + 4);
    int4 a2 = *(const int4*)(p0 + 8);  int4 a3 = *(const int4*)(p0 + 12);
    int4 b0 = *(const int4*)(p1);      int4 b1 = *(const int4*)(p1 + 4);
    int4 b2 = *(const int4*)(p1 + 8);  int4 b3 = *(const int4*)(p1 + 12);
    bmb[(size_t)row*256 + t]       = (ushort)pack16(a0, a1, a2, a3);
    bmb[(size_t)(row + 1)*256 + t] = (ushort)pack16(b0, b1, b2, b3);
    return;
  }

  int tx = t & 15, ty = t >> 4;
  int r0 = (bid & 63) * 64;
  int cb = bid >> 6;
  int c0 = cb * 64;
  float acc[4][4] = {};

  for (int k0 = 0; k0 < INF_; k0 += 64){
    int row = t >> 2, kc = (t & 3) * 16;
    #pragma unroll
    for (int u = 0; u < 4; u++){
      float4 v = *(const float4*)&hmat[(r0 + row)*INF_ + k0 + kc + 4*u];
      hsT[kc + 4*u + 0][row] = v.x;
      hsT[kc + 4*u + 1][row] = v.y;
      hsT[kc + 4*u + 2][row] = v.z;
      hsT[kc + 4*u + 3][row] = v.w;
    }
    #pragma unroll
    for (int u = 0; u < 4; u++){
      float4 v = *(const float4*)&W[(c0 + row)*INF_ + k0 + kc + 4*u];
      wsT[kc + 4*u + 0][row] = v.x;
      wsT[kc + 4*u + 1][row] = v.y;
      wsT[kc + 4*u + 2][row] = v.z;
      wsT[kc + 4*u + 3][row] = v.w;
    }
    __syncthreads();
    #pragma unroll 8
    for (int k = 0; k < 64; k++){
      float4 hv = *(const float4*)&hsT[k][ty*4];
      float4 wv = *(const float4*)&wsT[k][tx*4];
      float ha[4] = {hv.x, hv.y, hv.z, hv.w};
      float wa[4] = {wv.x, wv.y, wv.z, wv.w};
      #pragma unroll
      for (int a_ = 0; a_ < 4; a_++)
        #pragma unroll
        for (int b_ = 0; b_ < 4; b_++)
          acc[a_][b_] = fmaf(ha[a_], wa[b_], acc[a_][b_]);
    }
    __syncthreads();
  }

  float alv[4], arv[4];
  #pragma unroll
  for (int j = 0; j < 4; j++){ alv[j] = aw[tx*4 + j]; arv[j] = aw[64 + tx*4 + j]; }
  float rmax = -3.4e38f;
  #pragma unroll
  for (int qi = 0; qi < 4; qi++){
    int r = r0 + ty*4 + qi;
    float slp = 0.f, srp = 0.f;
    #pragma unroll
    for (int j = 0; j < 4; j++){
      slp = fmaf(acc[qi][j], alv[j], slp);
      srp = fmaf(acc[qi][j], arv[j], srp);
    }
    #pragma unroll
    for (int m = 1; m < 16; m <<= 1){
      slp += __shfl_xor(slp, m, 64);
      srp += __shfl_xor(srp, m, 64);
    }
    if (tx == 0){
      slT2[(size_t)cb*NN + r] = slp * L2E;
      srT2[(size_t)cb*NN + r] = srp * L2E;
      rmax = fmaxf(rmax, srp * L2E);
    }
  }
  if (tx == 0) smax_l[ty] = rmax;

  float* T = (float*)hsT;
  #pragma unroll
  for (int qi = 0; qi < 4; qi++)
    #pragma unroll
    for (int j = 0; j < 4; j++)
      T[(tx*4 + j)*65 + ty*4 + qi] = acc[qi][j];
  __syncthreads();
  if (t == 0){
    float m = smax_l[0];
    #pragma unroll
    for (int i = 1; i < 16; i++) m = fmaxf(m, smax_l[i]);
    atomicMax(srmax2 + cb, ford(m));
  }
  int c = t >> 2, rb = (t & 3) * 16;
  ushort u16[16];
  #pragma unroll
  for (int v = 0; v < 16; v++) u16[v] = bf16u(T[c*65 + rb + v]);
  *(uint4*)&gT[(size_t)(c0 + c)*NN + r0 + rb]     = *(uint4*)&u16[0];
  *(uint4*)&gT[(size_t)(c0 + c)*NN + r0 + rb + 8] = *(uint4*)&u16[8];
}

// ---- fused masked-softmax attention: r19 LDS-staged-B structure +
//      transcendental-free weights: w = fmax(E1*pe, E2*qe) with f32 LDS
//      tables pe=exp2(sr-srmax), qe=exp2(0.2(sr-srmax)); E1,E2 per-row
//      prologue scalars. Single accumulator set (identity: E1*pe>=E2*qe
//      iff sl+sr>=0, so fmax selects the lrelu branch exactly). ----
__launch_bounds__(512)
__global__ void k_attn(const short* __restrict__ gT, const float* __restrict__ slT2,
                       const float* __restrict__ srT2, const uint32_t* __restrict__ srmax2,
                       const uint32_t* __restrict__ bm,
                       __hip_bfloat16* __restrict__ num_p, float* __restrict__ den_p){
  __shared__ float    pelds[4][512];       // [head][j - jb]: exp2(sr - srmax)
  __shared__ float    qelds[4][512];       // [head][j - jb]: exp2(NEG*(sr - srmax))
  __shared__ uint32_t bmlds[64 * 18];      // [row][word]
  __shared__ short    Bst[2][4*64*40];     // [buf][head][row][40] (32 used + 8 pad)
  int t  = threadIdx.x;
  int w  = t >> 6, l = t & 63;
  int h  = w & 3, ihalf = w >> 2;
  int lr = l & 15, lg = l >> 4;
  int ib = blockIdx.x * BI;
  int i0 = ib + ihalf * 32;
  int jb = blockIdx.y * NJ;
  int js = blockIdx.y;

  // staging thread identity for B tiles
  int sh  = t >> 7;            // head 0..3
  int srw = (t >> 1) & 63;     // row 0..63
  int spt = t & 1;             // 16-short half 0..1
  const short* gsrc = gT + (size_t)(sh*HID + srw)*NN + jb + spt*16;
  short* ldst0 = &Bst[0][sh*2560 + srw*40 + spt*16];
  short* ldst1 = &Bst[1][sh*2560 + srw*40 + spt*16];

  // stage pe/qe tables (thread covers 4 j of head t>>7) + bitmask tile
  {
    int hh = t >> 7, jj = (t & 127) * 4;
    float smx = funord(srmax2[hh]);
    float4 v = *(const float4*)&srT2[(size_t)hh*NN + jb + jj];
    float sv[4] = {v.x, v.y, v.z, v.w};
    float pv[4], qv[4];
    #pragma unroll
    for (int q = 0; q < 4; q++){
      float s = sv[q] - smx;
      pv[q] = __builtin_amdgcn_exp2f(s);
      qv[q] = __builtin_amdgcn_exp2f(NEG * s);
    }
    *(float4*)&pelds[hh][jj] = make_float4(pv[0], pv[1], pv[2], pv[3]);
    *(float4*)&qelds[hh][jj] = make_float4(qv[0], qv[1], qv[2], qv[3]);
    int r = t >> 3, wd = (t & 7) * 2;
    uint2 vb = *(const uint2*)&bm[(size_t)(ib + r)*128 + (jb >> 5) + wd];
    bmlds[r*18 + wd]     = vb.x;
    bmlds[r*18 + wd + 1] = vb.y;
  }

  // per-row branch scales (4 exp2 per thread, prologue only)
  float srmaxh = funord(srmax2[h]);
  float E1[2], E2[2];
  #pragma unroll
  for (int m = 0; m < 2; m++){
    float slv = slT2[(size_t)h*NN + i0 + m*16 + lr];
    float x   = slv + srmaxh;
    float msh = fmaxf(x, NEG * x);
    E1[m] = __builtin_amdgcn_exp2f(x - msh);
    E2[m] = __builtin_amdgcn_exp2f(fmaf(NEG, x, -msh));
  }

  // prologue: stage step 0 B into buf 0
  {
    uint4 g0 = *(const uint4*)(gsrc);
    uint4 g1 = *(const uint4*)(gsrc + 8);
    *(uint4*)(ldst0)     = g0;
    *(uint4*)(ldst0 + 8) = g1;
  }
  __syncthreads();

  f32x4 acc[2][4] = {};
  f32x4 dacc[2]   = {};
  bf16x8 ones;
  #pragma unroll
  for (int q = 0; q < 8; q++) ones[q] = (short)0x3F80;

  const short* brd0 = &Bst[0][h*2560 + lr*40 + lg*8];
  const short* brd1 = &Bst[1][h*2560 + lr*40 + lg*8];

  bf16x8 Bb[4];
  #pragma unroll
  for (int n = 0; n < 4; n++)
    Bb[n] = *(const bf16x8*)(brd0 + n*640);

  int rowl0 = (ihalf*32 + lr) * 18;
  int rowl1 = (ihalf*32 + 16 + lr) * 18;

  #pragma unroll
  for (int s = 0; s < 16; s++){
    // issue next step's global loads early
    uint4 g0, g1;
    if (s < 15){
      g0 = *(const uint4*)(gsrc + (s+1)*32);
      g1 = *(const uint4*)(gsrc + (s+1)*32 + 8);
    }
    // current step's table slices + bm words (LDS-resident, broadcast reads)
    float4 p0 = *(const float4*)&pelds[h][s*32 + lg*8];
    float4 p1 = *(const float4*)&pelds[h][s*32 + lg*8 + 4];
    float4 q0 = *(const float4*)&qelds[h][s*32 + lg*8];
    float4 q1 = *(const float4*)&qelds[h][s*32 + lg*8 + 4];
    uint32_t w0c = bmlds[rowl0 + s];
    uint32_t w1c = bmlds[rowl1 + s];
    float pe[8] = {p0.x, p0.y, p0.z, p0.w, p1.x, p1.y, p1.z, p1.w};
    float qe[8] = {q0.x, q0.y, q0.z, q0.w, q1.x, q1.y, q1.z, q1.w};

    bf16x8 A[2];
    #pragma unroll
    for (int m = 0; m < 2; m++){
      uint32_t word = (m ? w1c : w0c) >> (lg*8);
      uint32_t pk[4];
      #pragma unroll
      for (int p = 0; p < 4; p++){
        float v0 = fmaxf(E1[m] * pe[2*p],     E2[m] * qe[2*p]);
        float v1 = fmaxf(E1[m] * pe[2*p + 1], E2[m] * qe[2*p + 1]);
        int m0 = (int)(word << (31 - 2*p)) >> 31;
        int m1 = (int)(word << (30 - 2*p)) >> 31;
        v0 = __uint_as_float(__float_as_uint(v0) & (uint32_t)m0);
        v1 = __uint_as_float(__float_as_uint(v1) & (uint32_t)m1);
        uint32_t u0 = __float_as_uint(v0) + 0x8000u;
        uint32_t u1 = __float_as_uint(v1) + 0x8000u;
        pk[p] = __builtin_amdgcn_perm(u1, u0, 0x07060302u);
      }
      A[m] = *(bf16x8*)pk;
    }

    __builtin_amdgcn_s_setprio(1);
    dacc[0] = __builtin_amdgcn_mfma_f32_16x16x32_bf16(A[0], ones, dacc[0], 0, 0, 0);
    #pragma unroll
    for (int n = 0; n < 4; n++)
      acc[0][n] = __builtin_amdgcn_mfma_f32_16x16x32_bf16(A[0], Bb[n], acc[0][n], 0, 0, 0);
    dacc[1] = __builtin_amdgcn_mfma_f32_16x16x32_bf16(A[1], ones, dacc[1], 0, 0, 0);
    #pragma unroll
    for (int n = 0; n < 4; n++)
      acc[1][n] = __builtin_amdgcn_mfma_f32_16x16x32_bf16(A[1], Bb[n], acc[1][n], 0, 0, 0);
    __builtin_amdgcn_s_setprio(0);

    if (s < 15){
      short* dst = ((s+1) & 1) ? ldst1 : ldst0;
      *(uint4*)(dst)     = g0;
      *(uint4*)(dst + 8) = g1;
      __syncthreads();
      const short* rd = ((s+1) & 1) ? brd1 : brd0;
      #pragma unroll
      for (int n = 0; n < 4; n++)
        Bb[n] = *(const bf16x8*)(rd + n*640);
    }
  }

  // num partials (bf16): row = i0+m*16+lg*4+r, col = h*64+n*16+lr
  #pragma unroll
  for (int m = 0; m < 2; m++)
    #pragma unroll
    for (int n = 0; n < 4; n++)
      #pragma unroll
      for (int r = 0; r < 4; r++)
        num_p[((size_t)js*NN + i0 + m*16 + lg*4 + r)*OUTC + h*HID + n*16 + lr] =
            __float2bfloat16(acc[m][n][r]);

  // den partials from ones-MFMA: row m*16+lg*4+r value sits in dacc[m][r] (any lr)
  if (lr == 0)
    #pragma unroll
    for (int m = 0; m < 2; m++)
      #pragma unroll
      for (int r = 0; r < 4; r++)
        den_p[((size_t)js*4 + h)*NN + i0 + m*16 + lg*4 + r] = dacc[m][r];
}

// ---- combine partials: out = sum(num)/sum(den), 2 cols/thread ----
__global__ void k_comb(const __hip_bfloat16* __restrict__ num_p,
                       const float* __restrict__ den_p, float* __restrict__ out){
  int t  = threadIdx.x;
  int r  = blockIdx.x*2 + (t >> 7);
  int c2 = (t & 127) * 2;
  int h  = c2 >> 6;
  float s0 = 0.f, s1 = 0.f, d = 0.f;
  #pragma unroll
  for (int js = 0; js < JSPLIT; js++){
    uint32_t u = *(const uint32_t*)&num_p[((size_t)js*NN + r)*OUTC + c2];
    s0 += __uint_as_float(u << 16);
    s1 += __uint_as_float(u & 0xffff0000u);
  }
  #pragma unroll
  for (int js = 0; js < JSPLIT; js++)
    d += den_p[((size_t)js*4 + h)*NN + r];
  float inv = 1.0f / d;
  *(float2*)&out[(size_t)r*OUTC + c2] = make_float2(s0*inv, s1*inv);
}

extern "C" void kernel_launch(void* const* d_in, const int* in_sizes, int n_in,
                              void* d_out, int out_size, void* d_ws, size_t ws_size,
                              hipStream_t stream){
  const float* hmat = (const float*)d_in[0];
  const int*   adj  = (const int*)d_in[1];     // int32 layout confirmed in r1
  const float* W    = (const float*)d_in[2];
  const float* aw   = (const float*)d_in[3];
  float* out = (float*)d_out;
  char*  ws  = (char*)d_ws;

  // ws layout (bytes), total ~21.6 MB (r15 proven)
  uint32_t* srmax2 = (uint32_t*)(ws);                      // 64 B
  float*    slT2   = (float*)(ws + 1024);                  // 64 KB
  float*    srT2   = (float*)(ws + 66560);                 // 64 KB
  short*    gT     = (short*)(ws + 132096);                // 2 MB   [256][4096] bf16
  float*    den_p  = (float*)(ws + 2229248);               // 512 KB [8][4][4096]
  __hip_bfloat16* num_p = (__hip_bfloat16*)(ws + 2753536); // 16.75 MB [8][4096][256]
  uint32_t* bmask  = (uint32_t*)(ws + 19530752);           // 2 MB   [4096][128] (byte-packed)

  hipMemsetAsync(ws, 0, 64, stream);   // srmax2 init
  hipLaunchKernelGGL(k_prep, dim3(2304), dim3(256), 0, stream,
                     adj, hmat, W, aw, (ushort*)bmask, gT, slT2, srT2, srmax2);
  hipLaunchKernelGGL(k_attn, dim3(NN/BI, JSPLIT), dim3(512), 0, stream,
                     gT, slT2, srT2, srmax2, bmask, num_p, den_p);
  hipLaunchKernelGGL(k_comb, dim3(NN/2), dim3(256), 0, stream, num_p, den_p, out);
}